// Round 11
// baseline (203.010 us; speedup 1.0000x reference)
//
#include <hip/hip_runtime.h>
#include <hip/hip_bf16.h>

#define DEV __device__ __forceinline__

typedef __attribute__((ext_vector_type(8))) short bf16x8;
typedef __attribute__((ext_vector_type(4))) float f32x4;

// N=65536 tokens, 8 heads, head dim 32, feature dim 256, block 256
static constexpr float QSCALE = 0.17677669529663687f; // 1/sqrt(32)
static constexpr float LOG2E  = 1.4426950408889634f;

DEV unsigned short f2bf(float f) {
    union { float f; unsigned int u; } a; a.f = f;
    unsigned int r = (a.u + 0x7fffu + ((a.u >> 16) & 1u)) >> 16; // RNE
    return (unsigned short)r;
}
DEV unsigned int pack2bf(float lo, float hi) {   // v_cvt_pk_bf16_f32 on gfx950
    float2 t; t.x = lo; t.y = hi;
    __hip_bfloat162 h = __float22bfloat162_rn(t);
    unsigned int u; __builtin_memcpy(&u, &h, 4);
    return u;
}
// exp2 for |x| <~ 0.2 (scores in log2 domain are tiny): quadratic Taylor,
// rel err < 2e-4 at |x|=0.15 — far below bf16 P-matrix rounding (0.4%).
DEV float exp2_small(float x) {
    return __builtin_fmaf(x, __builtin_fmaf(x, 0.2402265069591007f, 0.6931471805599453f), 1.0f);
}
DEV int bucketof(float v) {
    int b = (int)(v * 65536.0f);
    b = b < 0 ? 0 : b;
    b = b > 65535 ? 65535 : b;
    return b;
}

// ---------------- sort: stable argsort of coords[:,0] ----------------
__global__ void khist(const float* coords, unsigned int* hist) {
    int i = blockIdx.x * 256 + threadIdx.x;
    atomicAdd(&hist[bucketof(coords[i * 3])], 1u);
}

__global__ void kscan1(const unsigned int* hist, unsigned int* excl, unsigned int* aux) {
    __shared__ unsigned int s[256];
    int tid = threadIdx.x;
    int g = blockIdx.x * 256 + tid;
    unsigned int v = hist[g];
    s[tid] = v; __syncthreads();
    for (int off = 1; off < 256; off <<= 1) {
        unsigned int t = (tid >= off) ? s[tid - off] : 0u;
        __syncthreads();
        s[tid] += t;
        __syncthreads();
    }
    excl[g] = s[tid] - v;
    if (tid == 255) aux[blockIdx.x] = s[255];
}

__global__ void kscan2(unsigned int* aux) {
    __shared__ unsigned int s[256];
    int tid = threadIdx.x;
    unsigned int v = aux[tid];
    s[tid] = v; __syncthreads();
    for (int off = 1; off < 256; off <<= 1) {
        unsigned int t = (tid >= off) ? s[tid - off] : 0u;
        __syncthreads();
        s[tid] += t;
        __syncthreads();
    }
    aux[tid] = s[tid] - v;
}

__global__ void kscan3(unsigned int* excl, const unsigned int* aux) {
    int g = blockIdx.x * 256 + threadIdx.x;
    excl[g] += aux[blockIdx.x];
}

__global__ void kscatter(const float* coords, unsigned int* excl, unsigned int* memb) {
    int i = blockIdx.x * 256 + threadIdx.x;
    int b = bucketof(coords[i * 3]);
    unsigned int pos = atomicAdd(&excl[b], 1u);
    memb[pos] = (unsigned int)i;
}

__global__ void krank(const float* coords, const unsigned int* excl,
                      const unsigned int* memb, unsigned int* order) {
    int i = blockIdx.x * 256 + threadIdx.x;
    int b = bucketof(coords[i * 3]);
    unsigned int start = (b == 0) ? 0u : excl[b - 1];
    unsigned int end = excl[b];
    unsigned int ki = __float_as_uint(coords[i * 3]);
    unsigned int r = start;
    for (unsigned int s2 = start; s2 < end; ++s2) {
        unsigned int j = memb[s2];
        unsigned int kj = __float_as_uint(coords[j * 3]);
        if (kj < ki || (kj == ki && j < (unsigned int)i)) r++;
    }
    order[r] = (unsigned int)i;
}

// ---------------- weight prep + w2 fused ----------------
__global__ void kwprep(const float* wq, const float* wk, const float* wv,
                       const float* w_out, const float* ff1, const float* ff2,
                       const float* w_rpe,
                       unsigned short* wqkvb, unsigned short* woutb,
                       unsigned short* ff1b, unsigned short* ff2b, float* w2) {
    if (blockIdx.x < 136) {
        int i = blockIdx.x * 256 + threadIdx.x;   // 136*256 = 34816 elems
        if (i < 8192)        wqkvb[i] = f2bf(wq[i] * (QSCALE * LOG2E));
        else if (i < 16384)  wqkvb[i] = f2bf(wk[i - 8192]);
        else if (i < 24576)  wqkvb[i] = f2bf(wv[i - 16384]);
        else if (i < 32768)  woutb[i - 24576] = f2bf(w_out[i - 24576]);
        else if (i < 33792)  ff1b[i - 32768] = f2bf(ff1[i - 32768]);
        else                 ff2b[i - 33792] = f2bf(ff2[i - 33792]);
    } else {
        int p = blockIdx.x - 136;    // p = h*2 + c
        int h = p >> 1, c = p & 1;
        int tid = threadIdx.x;
        int d = tid >> 3, j = tid & 7;
        float v = w_rpe[(h * 32 + d) * 16 + c * 8 + j];
        float v2 = v * v;
        for (int m = 32; m >= 1; m >>= 1) v2 += __shfl_xor(v2, m);
        __shared__ float part[4];
        if ((tid & 63) == 0) part[tid >> 6] = v2;
        __syncthreads();
        if (tid == 0) w2[p] = (part[0] + part[1] + part[2] + part[3]) * (1.0f / 256.0f) * LOG2E;
    }
}

// ---------------- fused LN1 + QKV-gen + local attention, per (bucket,head) block ----------------
// Same structure as R10 (passed, 64 µs) + two changes:
//  (1) xnb/Qb chunk-XOR swizzle (16B chunk c of row t at c ^ ((t>>1)&3)):
//      turns the 8-way b128 read conflicts on unpadded 64 B rows into 2-way (free).
//  (2) exp2 -> 2-FMA quadratic Taylor (scores tiny; removes 1/4-rate transcendental floor).
// LDS: xnb 16384 + Qb 16384 + Kb 20480 + Vt 16896 + kext 2048 + Pst 9216 = 81408 -> 2 blocks/CU.
__global__ __launch_bounds__(256, 2) void kattn(
    const float* x, const float* g1, const float* be1,
    const unsigned short* wqkvb,
    const unsigned int* order, const float* coords, const float* w2,
    unsigned short* aobf)
{
    __shared__ unsigned short xnb[256][32];     // 16384 B  LN'd x, swizzled chunks
    __shared__ unsigned short Qb[256][32];      // 16384 B  swizzled chunks
    __shared__ unsigned short Kb[256][40];      // 20480 B  padded (conflict-free)
    __shared__ unsigned short Vt[32][264];      // 16896 B  [feature][permuted token]
    __shared__ unsigned short kext[256][4];     //  2048 B  {pc0,pc1,ge,0}
    __shared__ unsigned short Pst[4][16][72];   //  9216 B  per-wave chunk strip / O staging

    int bh = blockIdx.x;
    int b = bh >> 3, h = bh & 7;
    int tid = threadIdx.x, wave = tid >> 6, lane = tid & 63;
    int col = lane & 15, quad = lane >> 4;
    float w0 = w2[2 * h], w1 = w2[2 * h + 1];   // already * log2e

    // ---- staging A: gather x row, LN1 -> xnb (swizzled); coords -> kext ----
    float p0own, p1own;
    {
        int t = tid;
        int tok = (int)order[b * 256 + t];
        float a = coords[tok * 3 + 1], bb = coords[tok * 3 + 2];
        p0own = a; p1own = bb;
        float ge = w0 * a * a + w1 * bb * bb;
        uint2 kv;
        kv.x = pack2bf(a, bb);
        kv.y = pack2bf(ge, 0.f);
        *(uint2*)&kext[t][0] = kv;

        float xv[32];
        const float4* xr = (const float4*)(x + (size_t)tok * 32);
#pragma unroll
        for (int q4 = 0; q4 < 8; q4++) {
            float4 v4 = xr[q4];
            xv[q4 * 4 + 0] = v4.x; xv[q4 * 4 + 1] = v4.y; xv[q4 * 4 + 2] = v4.z; xv[q4 * 4 + 3] = v4.w;
        }
        float mu = 0.f;
#pragma unroll
        for (int d = 0; d < 32; d++) mu += xv[d];
        mu *= (1.0f / 32.0f);
        float var = 0.f;
#pragma unroll
        for (int d = 0; d < 32; d++) { float c = xv[d] - mu; var += c * c; }
        var *= (1.0f / 32.0f);
        float rstd = rsqrtf(var + 1e-5f);
        unsigned int pk[16];
#pragma unroll
        for (int w = 0; w < 16; w++) {
            float a2 = (xv[2 * w] - mu) * rstd * g1[2 * w] + be1[2 * w];
            float b2 = (xv[2 * w + 1] - mu) * rstd * g1[2 * w + 1] + be1[2 * w + 1];
            pk[w] = pack2bf(a2, b2);
        }
        int v = (t >> 1) & 3;                    // chunk swizzle key
        uint4* dst = (uint4*)&xnb[t][0];
#pragma unroll
        for (int w4 = 0; w4 < 4; w4++) {
            uint4 v4; v4.x = pk[w4*4]; v4.y = pk[w4*4+1]; v4.z = pk[w4*4+2]; v4.w = pk[w4*4+3];
            dst[w4 ^ v] = v4;                    // logical chunk w4 -> physical w4^v
        }
    }

    // weight A-fragments for this head (global 16 B loads, L2-resident): q/k/v x 2 tiles
    bf16x8 wfr[6];
#pragma unroll
    for (int g = 0; g < 3; g++)
#pragma unroll
        for (int mt = 0; mt < 2; mt++)
            wfr[g * 2 + mt] = *(const bf16x8*)(wqkvb + (size_t)(g * 256 + h * 32 + mt * 16 + col) * 32 + quad * 8);

    __syncthreads();

    // ---- staging B: Q/K/V = w @ xn^T via MFMA (C: m=feature quad*4+r, n=token col) ----
#pragma unroll
    for (int si = 0; si < 4; si++) {
        int token = wave * 64 + si * 16 + col;
        int vtk = (token >> 1) & 3;              // swizzle key of this token's row
        bf16x8 bfx = *(const bf16x8*)&xnb[token][(quad ^ vtk) * 8];
        f32x4 zz = { 0.f, 0.f, 0.f, 0.f };
        // Q -> Qb (swizzled): logical chunk lc = 2mt + (quad>>1), within-chunk (quad&1)*4
#pragma unroll
        for (int mt = 0; mt < 2; mt++) {
            f32x4 z = __builtin_amdgcn_mfma_f32_16x16x32_bf16(wfr[0 * 2 + mt], bfx, zz, 0, 0, 0);
            uint2 u; u.x = pack2bf(z[0], z[1]); u.y = pack2bf(z[2], z[3]);
            int lc = 2 * mt + (quad >> 1);
            *(uint2*)&Qb[token][(lc ^ vtk) * 8 + (quad & 1) * 4] = u;
        }
        // K (padded, unswizzled)
#pragma unroll
        for (int mt = 0; mt < 2; mt++) {
            f32x4 z = __builtin_amdgcn_mfma_f32_16x16x32_bf16(wfr[1 * 2 + mt], bfx, zz, 0, 0, 0);
            uint2 u; u.x = pack2bf(z[0], z[1]); u.y = pack2bf(z[2], z[3]);
            *(uint2*)&Kb[token][mt * 16 + quad * 4] = u;
        }
        // V -> Vt[feature][jinv(token)]  (jinv = inverse of the PV column permutation)
        int jinv = (token & ~63) + (token & 15) * 4 + ((token >> 4) & 3);
#pragma unroll
        for (int mt = 0; mt < 2; mt++) {
            f32x4 z = __builtin_amdgcn_mfma_f32_16x16x32_bf16(wfr[2 * 2 + mt], bfx, zz, 0, 0, 0);
#pragma unroll
            for (int r = 0; r < 4; r++)
                Vt[mt * 16 + quad * 4 + r][jinv] = f2bf(z[r]);
        }
    }
    __syncthreads();

    // extended-K fragments (bias cross terms)
    bf16x8 keext[16];
#pragma unroll
    for (int nt = 0; nt < 16; nt++) {
        uint2 kv = *(const uint2*)&kext[nt * 16 + col][0];
        unsigned int a0 = quad == 0 ? kv.x : 0u;
        unsigned int a1 = quad == 0 ? kv.y : 0u;
        bf16x8 f;
        f[0] = (short)(a0 & 0xffffu); f[1] = (short)(a0 >> 16);
        f[2] = (short)(a1 & 0xffffu); f[3] = 0;
        f[4] = 0; f[5] = 0; f[6] = 0; f[7] = 0;
        keext[nt] = f;
    }

    // V fragments: invariant across the 4 strips -> hoist to registers
    bf16x8 vfr0[8], vfr1[8];
#pragma unroll
    for (int c = 0; c < 4; c++) {
#pragma unroll
        for (int k2 = 0; k2 < 2; k2++) {
            vfr0[c * 2 + k2] = *(const bf16x8*)&Vt[col][c * 64 + k2 * 32 + quad * 8];
            vfr1[c * 2 + k2] = *(const bf16x8*)&Vt[16 + col][c * 64 + k2 * 32 + quad * 8];
        }
    }
    __syncthreads();   // all vfr/keext hoists complete before strip loop

    for (int si = 0; si < 4; si++) {
        int s = wave * 4 + si;                  // strip rows s*16 .. +15 (sorted-local)
        int trow = s * 16 + col;
        bf16x8 qa = *(const bf16x8*)&Qb[trow][(quad ^ ((trow >> 1) & 3)) * 8];
        float p0m = __shfl(p0own, si * 16 + col);
        float p1m = __shfl(p1own, si * 16 + col);
        unsigned int qp = quad == 0 ? pack2bf(2.0f * w0 * p0m, 2.0f * w1 * p1m) : 0u;
        bf16x8 qe;
        qe[0] = (short)(qp & 0xffffu); qe[1] = (short)(qp >> 16);
        qe[2] = (short)(quad == 0 ? 0xBF80 : 0); qe[3] = 0;   // -1.0 bf16
        qe[4] = 0; qe[5] = 0; qe[6] = 0; qe[7] = 0;

        f32x4 acc[16];
#pragma unroll
        for (int nt = 0; nt < 16; nt++) {
            bf16x8 kb = *(const bf16x8*)&Kb[nt * 16 + col][quad * 8];
            f32x4 z = { 0.f, 0.f, 0.f, 0.f };
            z = __builtin_amdgcn_mfma_f32_16x16x32_bf16(qa, kb, z, 0, 0, 0);
            acc[nt] = __builtin_amdgcn_mfma_f32_16x16x32_bf16(qe, keext[nt], z, 0, 0, 0);
        }

        // scores in log2 domain, |x| tiny -> 2-FMA Taylor exp2 (no transcendental)
        float rsum[4] = { 0.f, 0.f, 0.f, 0.f };
        f32x4 o0 = { 0.f, 0.f, 0.f, 0.f }, o1 = { 0.f, 0.f, 0.f, 0.f };
#pragma unroll
        for (int c = 0; c < 4; c++) {
#pragma unroll
            for (int r = 0; r < 4; r++) {
                float e0 = exp2_small(acc[c * 4 + 0][r]);
                float e1 = exp2_small(acc[c * 4 + 1][r]);
                float e2 = exp2_small(acc[c * 4 + 2][r]);
                float e3 = exp2_small(acc[c * 4 + 3][r]);
                rsum[r] += (e0 + e1) + (e2 + e3);
                uint2 pk;
                pk.x = pack2bf(e0, e1);
                pk.y = pack2bf(e2, e3);
                *(uint2*)&Pst[wave][quad * 4 + r][col * 4] = pk;  // kloc = col*4+t
            }
#pragma unroll
            for (int k2 = 0; k2 < 2; k2++) {
                bf16x8 pa = *(const bf16x8*)&Pst[wave][col][k2 * 32 + quad * 8];
                o0 = __builtin_amdgcn_mfma_f32_16x16x32_bf16(pa, vfr0[c * 2 + k2], o0, 0, 0, 0);
                o1 = __builtin_amdgcn_mfma_f32_16x16x32_bf16(pa, vfr1[c * 2 + k2], o1, 0, 0, 0);
            }
        }

        // scale by 1/sum, stage O strip, full-line 16 B stores to private region
#pragma unroll
        for (int r = 0; r < 4; r++) {
            float su = rsum[r];
            su += __shfl_xor(su, 1); su += __shfl_xor(su, 2);
            su += __shfl_xor(su, 4); su += __shfl_xor(su, 8);
            float rl = __builtin_amdgcn_rcpf(su);
            Pst[wave][quad * 4 + r][col]      = f2bf(o0[r] * rl);
            Pst[wave][quad * 4 + r][col + 16] = f2bf(o1[r] * rl);
        }
        int orow = lane >> 2, opart = lane & 3;
        uint4 ov = *(const uint4*)&Pst[wave][orow][opart * 8];
        *(uint4*)(aobf + (size_t)bh * 8192 + (size_t)(s * 16 + orow) * 32 + opart * 8) = ov;
    }
}

// ---------------- out-proj + residual + LN2 + FFN + residual (sorted rows; x/out via order) ----------------
__global__ __launch_bounds__(256) void kfinal(
    const float* x, const unsigned short* aobf, const unsigned int* order,
    const unsigned short* woutb, const float* b_out,
    const float* g2, const float* be2,
    const unsigned short* ff1b, const float* ffb1,
    const unsigned short* ff2b, const float* ffb2,
    float* out)
{
    __shared__ unsigned short strip[4][16][40];
    int tid = threadIdx.x;
    int wave = tid >> 6, lane = tid & 63, col = lane & 15, quad = lane >> 4;
    int base = blockIdx.x * 128;          // sorted-row base
    int bfix = blockIdx.x >> 1;           // bucket (uniform per block)
    int rbase = (blockIdx.x & 1) * 128;   // row offset within bucket

    bf16x8 wof[16];
#pragma unroll
    for (int ct = 0; ct < 2; ct++)
#pragma unroll
        for (int ks = 0; ks < 8; ks++)
            wof[ct * 8 + ks] = *(const bf16x8*)(woutb + (size_t)(ct * 16 + col) * 256 + ks * 32 + quad * 8);
    bf16x8 w1f[2], w2f[2];
#pragma unroll
    for (int ct = 0; ct < 2; ct++) {
        w1f[ct] = *(const bf16x8*)(ff1b + (ct * 16 + col) * 32 + quad * 8);
        w2f[ct] = *(const bf16x8*)(ff2b + (ct * 16 + col) * 32 + quad * 8);
    }
    float bo0 = b_out[col], bo1 = b_out[col + 16];
    float g20 = g2[col], g21 = g2[col + 16], be20 = be2[col], be21 = be2[col + 16];
    float fb10 = ffb1[col], fb11 = ffb1[col + 16];
    float fb20 = ffb2[col], fb21 = ffb2[col + 16];

    for (int rr = 0; rr < 2; rr++) {
        int rt = wave * 2 + rr;
        int rloc0 = rbase + rt * 16;      // sorted-local row base of this 16-tile

        // out-proj: feature chunk ks lives in head-ks private region of this bucket
        f32x4 a0 = { 0.f, 0.f, 0.f, 0.f }, a1 = { 0.f, 0.f, 0.f, 0.f };
#pragma unroll
        for (int ks = 0; ks < 8; ks++) {
            bf16x8 af = *(const bf16x8*)(aobf + (size_t)(bfix * 8 + ks) * 8192
                                         + (size_t)(rloc0 + col) * 32 + quad * 8);
            a0 = __builtin_amdgcn_mfma_f32_16x16x32_bf16(af, wof[ks], a0, 0, 0, 0);
            a1 = __builtin_amdgcn_mfma_f32_16x16x32_bf16(af, wof[8 + ks], a1, 0, 0, 0);
        }

        int trow[4];
#pragma unroll
        for (int r = 0; r < 4; r++) trow[r] = (int)order[base + rt * 16 + quad * 4 + r];

#pragma unroll
        for (int r = 0; r < 4; r++) {
            a0[r] += x[(size_t)trow[r] * 32 + col] + bo0;
            a1[r] += x[(size_t)trow[r] * 32 + 16 + col] + bo1;
        }

        f32x4 xn0, xn1;
#pragma unroll
        for (int r = 0; r < 4; r++) {
            float s = a0[r] + a1[r];
            s += __shfl_xor(s, 1); s += __shfl_xor(s, 2); s += __shfl_xor(s, 4); s += __shfl_xor(s, 8);
            float mu = s * (1.0f / 32.0f);
            float c0 = a0[r] - mu, c1 = a1[r] - mu;
            float v = c0 * c0 + c1 * c1;
            v += __shfl_xor(v, 1); v += __shfl_xor(v, 2); v += __shfl_xor(v, 4); v += __shfl_xor(v, 8);
            float rstd = rsqrtf(v * (1.0f / 32.0f) + 1e-5f);
            xn0[r] = c0 * rstd * g20 + be20;
            xn1[r] = c1 * rstd * g21 + be21;
        }

#pragma unroll
        for (int r = 0; r < 4; r++) {
            strip[wave][quad * 4 + r][col]      = f2bf(xn0[r]);
            strip[wave][quad * 4 + r][col + 16] = f2bf(xn1[r]);
        }
        bf16x8 af1 = *(const bf16x8*)&strip[wave][col][quad * 8];
        f32x4 z = { 0.f, 0.f, 0.f, 0.f };
        f32x4 h0 = __builtin_amdgcn_mfma_f32_16x16x32_bf16(af1, w1f[0], z, 0, 0, 0);
        f32x4 h1 = __builtin_amdgcn_mfma_f32_16x16x32_bf16(af1, w1f[1], z, 0, 0, 0);
#pragma unroll
        for (int r = 0; r < 4; r++) {
            h0[r] = fmaxf(h0[r] + fb10, 0.f);
            h1[r] = fmaxf(h1[r] + fb11, 0.f);
        }

#pragma unroll
        for (int r = 0; r < 4; r++) {
            strip[wave][quad * 4 + r][col]      = f2bf(h0[r]);
            strip[wave][quad * 4 + r][col + 16] = f2bf(h1[r]);
        }
        bf16x8 af2 = *(const bf16x8*)&strip[wave][col][quad * 8];
        f32x4 f0 = __builtin_amdgcn_mfma_f32_16x16x32_bf16(af2, w2f[0], z, 0, 0, 0);
        f32x4 f1 = __builtin_amdgcn_mfma_f32_16x16x32_bf16(af2, w2f[1], z, 0, 0, 0);

#pragma unroll
        for (int r = 0; r < 4; r++) {
            out[(size_t)trow[r] * 32 + col]      = a0[r] + f0[r] + fb20;
            out[(size_t)trow[r] * 32 + 16 + col] = a1[r] + f1[r] + fb21;
        }
    }
}

extern "C" void kernel_launch(void* const* d_in, const int* in_sizes, int n_in,
                              void* d_out, int out_size, void* d_ws, size_t ws_size,
                              hipStream_t stream) {
    (void)in_sizes; (void)n_in; (void)out_size; (void)ws_size;
    const float* x      = (const float*)d_in[0];
    const float* coords = (const float*)d_in[1];
    const float* wq     = (const float*)d_in[2];
    const float* wk     = (const float*)d_in[3];
    const float* wv     = (const float*)d_in[4];
    const float* w_rpe  = (const float*)d_in[5];
    const float* w_out  = (const float*)d_in[6];
    const float* b_out  = (const float*)d_in[7];
    const float* g1     = (const float*)d_in[8];
    const float* be1    = (const float*)d_in[9];
    const float* g2     = (const float*)d_in[10];
    const float* be2    = (const float*)d_in[11];
    const float* ffw1   = (const float*)d_in[12];
    const float* ffb1   = (const float*)d_in[13];
    const float* ffw2   = (const float*)d_in[14];
    const float* ffb2   = (const float*)d_in[15];
    float* out = (float*)d_out;

    char* ws = (char*)d_ws;
    unsigned int* hist  = (unsigned int*)(ws);                       // 64K u32
    unsigned int* excl  = (unsigned int*)(ws + 256 * 1024);          // 64K u32
    unsigned int* aux   = (unsigned int*)(ws + 512 * 1024);          // 256 u32
    unsigned int* memb  = (unsigned int*)(ws + 768 * 1024);          // 64K u32
    unsigned int* order = (unsigned int*)(ws + 1024 * 1024);         // 64K u32
    float*        w2    = (float*)(ws + 1280 * 1024);                // 16 f32
    unsigned short* wqkvb = (unsigned short*)(ws + 1536 * 1024);     // 48 KB
    unsigned short* woutb = wqkvb + 24576;
    unsigned short* ff1b  = woutb + 8192;
    unsigned short* ff2b  = ff1b + 1024;
    unsigned short* aobf = (unsigned short*)(ws + (size_t)100 * 1048576); // 32 MiB [(b*8+h)][256][32]

    hipMemsetAsync(hist, 0, 65536 * sizeof(unsigned int), stream);
    khist   <<<256, 256, 0, stream>>>(coords, hist);
    kscan1  <<<256, 256, 0, stream>>>(hist, excl, aux);
    kscan2  <<<1,   256, 0, stream>>>(aux);
    kscan3  <<<256, 256, 0, stream>>>(excl, aux);
    kscatter<<<256, 256, 0, stream>>>(coords, excl, memb);
    krank   <<<256, 256, 0, stream>>>(coords, excl, memb, order);
    kwprep  <<<152, 256, 0, stream>>>(wq, wk, wv, w_out, ffw1, ffw2, w_rpe,
                                      wqkvb, woutb, ff1b, ff2b, w2);
    kattn   <<<2048,256, 0, stream>>>(x, g1, be1, wqkvb, order, coords, w2, aobf);
    kfinal  <<<512, 256, 0, stream>>>(x, aobf, order, woutb, b_out, g2, be2,
                                      ff1b, ffb1, ff2b, ffb2, out);
}

// Round 12
// 175.424 us; speedup vs baseline: 1.1572x; 1.1572x over previous
//
#include <hip/hip_runtime.h>
#include <hip/hip_bf16.h>

#define DEV __device__ __forceinline__

typedef __attribute__((ext_vector_type(8))) short bf16x8;
typedef __attribute__((ext_vector_type(4))) float f32x4;

// N=65536 tokens, 8 heads, head dim 32, feature dim 256, block 256
static constexpr float QSCALE = 0.17677669529663687f; // 1/sqrt(32)
static constexpr float LOG2E  = 1.4426950408889634f;

DEV unsigned short f2bf(float f) {
    union { float f; unsigned int u; } a; a.f = f;
    unsigned int r = (a.u + 0x7fffu + ((a.u >> 16) & 1u)) >> 16; // RNE
    return (unsigned short)r;
}
DEV unsigned int pack2bf(float lo, float hi) {   // v_cvt_pk_bf16_f32 on gfx950
    float2 t; t.x = lo; t.y = hi;
    __hip_bfloat162 h = __float22bfloat162_rn(t);
    unsigned int u; __builtin_memcpy(&u, &h, 4);
    return u;
}
DEV int bucketof(float v) {
    int b = (int)(v * 65536.0f);
    b = b < 0 ? 0 : b;
    b = b > 65535 ? 65535 : b;
    return b;
}

// ---------------- sort: stable argsort of coords[:,0] ----------------
__global__ void khist(const float* coords, unsigned int* hist) {
    int i = blockIdx.x * 256 + threadIdx.x;
    atomicAdd(&hist[bucketof(coords[i * 3])], 1u);
}

__global__ void kscan1(const unsigned int* hist, unsigned int* excl, unsigned int* aux) {
    __shared__ unsigned int s[256];
    int tid = threadIdx.x;
    int g = blockIdx.x * 256 + tid;
    unsigned int v = hist[g];
    s[tid] = v; __syncthreads();
    for (int off = 1; off < 256; off <<= 1) {
        unsigned int t = (tid >= off) ? s[tid - off] : 0u;
        __syncthreads();
        s[tid] += t;
        __syncthreads();
    }
    excl[g] = s[tid] - v;
    if (tid == 255) aux[blockIdx.x] = s[255];
}

__global__ void kscan2(unsigned int* aux) {
    __shared__ unsigned int s[256];
    int tid = threadIdx.x;
    unsigned int v = aux[tid];
    s[tid] = v; __syncthreads();
    for (int off = 1; off < 256; off <<= 1) {
        unsigned int t = (tid >= off) ? s[tid - off] : 0u;
        __syncthreads();
        s[tid] += t;
        __syncthreads();
    }
    aux[tid] = s[tid] - v;
}

__global__ void kscan3(unsigned int* excl, const unsigned int* aux) {
    int g = blockIdx.x * 256 + threadIdx.x;
    excl[g] += aux[blockIdx.x];
}

__global__ void kscatter(const float* coords, unsigned int* excl, unsigned int* memb) {
    int i = blockIdx.x * 256 + threadIdx.x;
    int b = bucketof(coords[i * 3]);
    unsigned int pos = atomicAdd(&excl[b], 1u);
    memb[pos] = (unsigned int)i;
}

__global__ void krank(const float* coords, const unsigned int* excl,
                      const unsigned int* memb, unsigned int* order) {
    int i = blockIdx.x * 256 + threadIdx.x;
    int b = bucketof(coords[i * 3]);
    unsigned int start = (b == 0) ? 0u : excl[b - 1];
    unsigned int end = excl[b];
    unsigned int ki = __float_as_uint(coords[i * 3]);
    unsigned int r = start;
    for (unsigned int s2 = start; s2 < end; ++s2) {
        unsigned int j = memb[s2];
        unsigned int kj = __float_as_uint(coords[j * 3]);
        if (kj < ki || (kj == ki && j < (unsigned int)i)) r++;
    }
    order[r] = (unsigned int)i;
}

// ---------------- weight prep + w2 fused ----------------
__global__ void kwprep(const float* wq, const float* wk, const float* wv,
                       const float* w_out, const float* ff1, const float* ff2,
                       const float* w_rpe,
                       unsigned short* wqkvb, unsigned short* woutb,
                       unsigned short* ff1b, unsigned short* ff2b, float* w2) {
    if (blockIdx.x < 136) {
        int i = blockIdx.x * 256 + threadIdx.x;   // 136*256 = 34816 elems
        if (i < 8192)        wqkvb[i] = f2bf(wq[i] * (QSCALE * LOG2E));
        else if (i < 16384)  wqkvb[i] = f2bf(wk[i - 8192]);
        else if (i < 24576)  wqkvb[i] = f2bf(wv[i - 16384]);
        else if (i < 32768)  woutb[i - 24576] = f2bf(w_out[i - 24576]);
        else if (i < 33792)  ff1b[i - 32768] = f2bf(ff1[i - 32768]);
        else                 ff2b[i - 33792] = f2bf(ff2[i - 33792]);
    } else {
        int p = blockIdx.x - 136;    // p = h*2 + c
        int h = p >> 1, c = p & 1;
        int tid = threadIdx.x;
        int d = tid >> 3, j = tid & 7;
        float v = w_rpe[(h * 32 + d) * 16 + c * 8 + j];
        float v2 = v * v;
        for (int m = 32; m >= 1; m >>= 1) v2 += __shfl_xor(v2, m);
        __shared__ float part[4];
        if ((tid & 63) == 0) part[tid >> 6] = v2;
        __syncthreads();
        if (tid == 0) w2[p] = (part[0] + part[1] + part[2] + part[3]) * (1.0f / 256.0f) * LOG2E;
    }
}

// ---------------- fused LN1 + QKV-gen + local attention, per (bucket,head) block ----------------
// R10 structure (passed, 64 µs, clean 38/33 MB traffic) + ONE change:
//   xnb/Qb chunk-XOR swizzle (16B chunk c of row t at c ^ ((t>>1)&3)) — turns the
//   8-way b128 read conflicts on unpadded 64 B rows into 2-way (free per m136).
//   Hardware v_exp_f32 kept (R11's Taylor caused register spills -> 70 MB scratch traffic).
// LDS: xnb 16384 + Qb 16384 + Kb 20480 + Vt 16896 + kext 2048 + Pst 9216 = 81408 -> 2 blocks/CU.
__global__ __launch_bounds__(256, 2) void kattn(
    const float* x, const float* g1, const float* be1,
    const unsigned short* wqkvb,
    const unsigned int* order, const float* coords, const float* w2,
    unsigned short* aobf)
{
    __shared__ unsigned short xnb[256][32];     // 16384 B  LN'd x, swizzled chunks
    __shared__ unsigned short Qb[256][32];      // 16384 B  swizzled chunks
    __shared__ unsigned short Kb[256][40];      // 20480 B  padded (conflict-free)
    __shared__ unsigned short Vt[32][264];      // 16896 B  [feature][permuted token]
    __shared__ unsigned short kext[256][4];     //  2048 B  {pc0,pc1,ge,0}
    __shared__ unsigned short Pst[4][16][72];   //  9216 B  per-wave chunk strip / O staging

    int bh = blockIdx.x;
    int b = bh >> 3, h = bh & 7;
    int tid = threadIdx.x, wave = tid >> 6, lane = tid & 63;
    int col = lane & 15, quad = lane >> 4;
    float w0 = w2[2 * h], w1 = w2[2 * h + 1];   // already * log2e

    // ---- staging A: gather x row, LN1 -> xnb (swizzled); coords -> kext ----
    float p0own, p1own;
    {
        int t = tid;
        int tok = (int)order[b * 256 + t];
        float a = coords[tok * 3 + 1], bb = coords[tok * 3 + 2];
        p0own = a; p1own = bb;
        float ge = w0 * a * a + w1 * bb * bb;
        uint2 kv;
        kv.x = pack2bf(a, bb);
        kv.y = pack2bf(ge, 0.f);
        *(uint2*)&kext[t][0] = kv;

        float xv[32];
        const float4* xr = (const float4*)(x + (size_t)tok * 32);
#pragma unroll
        for (int q4 = 0; q4 < 8; q4++) {
            float4 v4 = xr[q4];
            xv[q4 * 4 + 0] = v4.x; xv[q4 * 4 + 1] = v4.y; xv[q4 * 4 + 2] = v4.z; xv[q4 * 4 + 3] = v4.w;
        }
        float mu = 0.f;
#pragma unroll
        for (int d = 0; d < 32; d++) mu += xv[d];
        mu *= (1.0f / 32.0f);
        float var = 0.f;
#pragma unroll
        for (int d = 0; d < 32; d++) { float c = xv[d] - mu; var += c * c; }
        var *= (1.0f / 32.0f);
        float rstd = rsqrtf(var + 1e-5f);
        unsigned int pk[16];
#pragma unroll
        for (int w = 0; w < 16; w++) {
            float a2 = (xv[2 * w] - mu) * rstd * g1[2 * w] + be1[2 * w];
            float b2 = (xv[2 * w + 1] - mu) * rstd * g1[2 * w + 1] + be1[2 * w + 1];
            pk[w] = pack2bf(a2, b2);
        }
        int v = (t >> 1) & 3;                    // chunk swizzle key
        uint4* dst = (uint4*)&xnb[t][0];
#pragma unroll
        for (int w4 = 0; w4 < 4; w4++) {
            uint4 v4; v4.x = pk[w4*4]; v4.y = pk[w4*4+1]; v4.z = pk[w4*4+2]; v4.w = pk[w4*4+3];
            dst[w4 ^ v] = v4;                    // logical chunk w4 -> physical w4^v
        }
    }

    // weight A-fragments for this head (global 16 B loads, L2-resident): q/k/v x 2 tiles
    bf16x8 wfr[6];
#pragma unroll
    for (int g = 0; g < 3; g++)
#pragma unroll
        for (int mt = 0; mt < 2; mt++)
            wfr[g * 2 + mt] = *(const bf16x8*)(wqkvb + (size_t)(g * 256 + h * 32 + mt * 16 + col) * 32 + quad * 8);

    __syncthreads();

    // ---- staging B: Q/K/V = w @ xn^T via MFMA (C: m=feature quad*4+r, n=token col) ----
#pragma unroll
    for (int si = 0; si < 4; si++) {
        int token = wave * 64 + si * 16 + col;
        int vtk = (token >> 1) & 3;              // swizzle key of this token's row
        bf16x8 bfx = *(const bf16x8*)&xnb[token][(quad ^ vtk) * 8];
        f32x4 zz = { 0.f, 0.f, 0.f, 0.f };
        // Q -> Qb (swizzled): logical chunk lc = 2mt + (quad>>1), within-chunk (quad&1)*4
#pragma unroll
        for (int mt = 0; mt < 2; mt++) {
            f32x4 z = __builtin_amdgcn_mfma_f32_16x16x32_bf16(wfr[0 * 2 + mt], bfx, zz, 0, 0, 0);
            uint2 u; u.x = pack2bf(z[0], z[1]); u.y = pack2bf(z[2], z[3]);
            int lc = 2 * mt + (quad >> 1);
            *(uint2*)&Qb[token][(lc ^ vtk) * 8 + (quad & 1) * 4] = u;
        }
        // K (padded, unswizzled)
#pragma unroll
        for (int mt = 0; mt < 2; mt++) {
            f32x4 z = __builtin_amdgcn_mfma_f32_16x16x32_bf16(wfr[1 * 2 + mt], bfx, zz, 0, 0, 0);
            uint2 u; u.x = pack2bf(z[0], z[1]); u.y = pack2bf(z[2], z[3]);
            *(uint2*)&Kb[token][mt * 16 + quad * 4] = u;
        }
        // V -> Vt[feature][jinv(token)]  (jinv = inverse of the PV column permutation)
        int jinv = (token & ~63) + (token & 15) * 4 + ((token >> 4) & 3);
#pragma unroll
        for (int mt = 0; mt < 2; mt++) {
            f32x4 z = __builtin_amdgcn_mfma_f32_16x16x32_bf16(wfr[2 * 2 + mt], bfx, zz, 0, 0, 0);
#pragma unroll
            for (int r = 0; r < 4; r++)
                Vt[mt * 16 + quad * 4 + r][jinv] = f2bf(z[r]);
        }
    }
    __syncthreads();

    // extended-K fragments (bias cross terms)
    bf16x8 keext[16];
#pragma unroll
    for (int nt = 0; nt < 16; nt++) {
        uint2 kv = *(const uint2*)&kext[nt * 16 + col][0];
        unsigned int a0 = quad == 0 ? kv.x : 0u;
        unsigned int a1 = quad == 0 ? kv.y : 0u;
        bf16x8 f;
        f[0] = (short)(a0 & 0xffffu); f[1] = (short)(a0 >> 16);
        f[2] = (short)(a1 & 0xffffu); f[3] = 0;
        f[4] = 0; f[5] = 0; f[6] = 0; f[7] = 0;
        keext[nt] = f;
    }

    // V fragments: invariant across the 4 strips -> hoist to registers
    bf16x8 vfr0[8], vfr1[8];
#pragma unroll
    for (int c = 0; c < 4; c++) {
#pragma unroll
        for (int k2 = 0; k2 < 2; k2++) {
            vfr0[c * 2 + k2] = *(const bf16x8*)&Vt[col][c * 64 + k2 * 32 + quad * 8];
            vfr1[c * 2 + k2] = *(const bf16x8*)&Vt[16 + col][c * 64 + k2 * 32 + quad * 8];
        }
    }
    __syncthreads();   // all vfr/keext hoists complete before strip loop

    for (int si = 0; si < 4; si++) {
        int s = wave * 4 + si;                  // strip rows s*16 .. +15 (sorted-local)
        int trow = s * 16 + col;
        bf16x8 qa = *(const bf16x8*)&Qb[trow][(quad ^ ((trow >> 1) & 3)) * 8];
        float p0m = __shfl(p0own, si * 16 + col);
        float p1m = __shfl(p1own, si * 16 + col);
        unsigned int qp = quad == 0 ? pack2bf(2.0f * w0 * p0m, 2.0f * w1 * p1m) : 0u;
        bf16x8 qe;
        qe[0] = (short)(qp & 0xffffu); qe[1] = (short)(qp >> 16);
        qe[2] = (short)(quad == 0 ? 0xBF80 : 0); qe[3] = 0;   // -1.0 bf16
        qe[4] = 0; qe[5] = 0; qe[6] = 0; qe[7] = 0;

        f32x4 acc[16];
#pragma unroll
        for (int nt = 0; nt < 16; nt++) {
            bf16x8 kb = *(const bf16x8*)&Kb[nt * 16 + col][quad * 8];
            f32x4 z = { 0.f, 0.f, 0.f, 0.f };
            z = __builtin_amdgcn_mfma_f32_16x16x32_bf16(qa, kb, z, 0, 0, 0);
            acc[nt] = __builtin_amdgcn_mfma_f32_16x16x32_bf16(qe, keext[nt], z, 0, 0, 0);
        }

        // scores in log2 domain -> hardware exp2 (R10-proven; Taylor spilled regs)
        float rsum[4] = { 0.f, 0.f, 0.f, 0.f };
        f32x4 o0 = { 0.f, 0.f, 0.f, 0.f }, o1 = { 0.f, 0.f, 0.f, 0.f };
#pragma unroll
        for (int c = 0; c < 4; c++) {
#pragma unroll
            for (int r = 0; r < 4; r++) {
                float e0 = __builtin_amdgcn_exp2f(acc[c * 4 + 0][r]);
                float e1 = __builtin_amdgcn_exp2f(acc[c * 4 + 1][r]);
                float e2 = __builtin_amdgcn_exp2f(acc[c * 4 + 2][r]);
                float e3 = __builtin_amdgcn_exp2f(acc[c * 4 + 3][r]);
                rsum[r] += (e0 + e1) + (e2 + e3);
                uint2 pk;
                pk.x = pack2bf(e0, e1);
                pk.y = pack2bf(e2, e3);
                *(uint2*)&Pst[wave][quad * 4 + r][col * 4] = pk;  // kloc = col*4+t
            }
#pragma unroll
            for (int k2 = 0; k2 < 2; k2++) {
                bf16x8 pa = *(const bf16x8*)&Pst[wave][col][k2 * 32 + quad * 8];
                o0 = __builtin_amdgcn_mfma_f32_16x16x32_bf16(pa, vfr0[c * 2 + k2], o0, 0, 0, 0);
                o1 = __builtin_amdgcn_mfma_f32_16x16x32_bf16(pa, vfr1[c * 2 + k2], o1, 0, 0, 0);
            }
        }

        // scale by 1/sum, stage O strip, full-line 16 B stores to private region
#pragma unroll
        for (int r = 0; r < 4; r++) {
            float su = rsum[r];
            su += __shfl_xor(su, 1); su += __shfl_xor(su, 2);
            su += __shfl_xor(su, 4); su += __shfl_xor(su, 8);
            float rl = __builtin_amdgcn_rcpf(su);
            Pst[wave][quad * 4 + r][col]      = f2bf(o0[r] * rl);
            Pst[wave][quad * 4 + r][col + 16] = f2bf(o1[r] * rl);
        }
        int orow = lane >> 2, opart = lane & 3;
        uint4 ov = *(const uint4*)&Pst[wave][orow][opart * 8];
        *(uint4*)(aobf + (size_t)bh * 8192 + (size_t)(s * 16 + orow) * 32 + opart * 8) = ov;
    }
}

// ---------------- out-proj + residual + LN2 + FFN + residual (sorted rows; x/out via order) ----------------
__global__ __launch_bounds__(256) void kfinal(
    const float* x, const unsigned short* aobf, const unsigned int* order,
    const unsigned short* woutb, const float* b_out,
    const float* g2, const float* be2,
    const unsigned short* ff1b, const float* ffb1,
    const unsigned short* ff2b, const float* ffb2,
    float* out)
{
    __shared__ unsigned short strip[4][16][40];
    int tid = threadIdx.x;
    int wave = tid >> 6, lane = tid & 63, col = lane & 15, quad = lane >> 4;
    int base = blockIdx.x * 128;          // sorted-row base
    int bfix = blockIdx.x >> 1;           // bucket (uniform per block)
    int rbase = (blockIdx.x & 1) * 128;   // row offset within bucket

    bf16x8 wof[16];
#pragma unroll
    for (int ct = 0; ct < 2; ct++)
#pragma unroll
        for (int ks = 0; ks < 8; ks++)
            wof[ct * 8 + ks] = *(const bf16x8*)(woutb + (size_t)(ct * 16 + col) * 256 + ks * 32 + quad * 8);
    bf16x8 w1f[2], w2f[2];
#pragma unroll
    for (int ct = 0; ct < 2; ct++) {
        w1f[ct] = *(const bf16x8*)(ff1b + (ct * 16 + col) * 32 + quad * 8);
        w2f[ct] = *(const bf16x8*)(ff2b + (ct * 16 + col) * 32 + quad * 8);
    }
    float bo0 = b_out[col], bo1 = b_out[col + 16];
    float g20 = g2[col], g21 = g2[col + 16], be20 = be2[col], be21 = be2[col + 16];
    float fb10 = ffb1[col], fb11 = ffb1[col + 16];
    float fb20 = ffb2[col], fb21 = ffb2[col + 16];

    for (int rr = 0; rr < 2; rr++) {
        int rt = wave * 2 + rr;
        int rloc0 = rbase + rt * 16;      // sorted-local row base of this 16-tile

        // out-proj: feature chunk ks lives in head-ks private region of this bucket
        f32x4 a0 = { 0.f, 0.f, 0.f, 0.f }, a1 = { 0.f, 0.f, 0.f, 0.f };
#pragma unroll
        for (int ks = 0; ks < 8; ks++) {
            bf16x8 af = *(const bf16x8*)(aobf + (size_t)(bfix * 8 + ks) * 8192
                                         + (size_t)(rloc0 + col) * 32 + quad * 8);
            a0 = __builtin_amdgcn_mfma_f32_16x16x32_bf16(af, wof[ks], a0, 0, 0, 0);
            a1 = __builtin_amdgcn_mfma_f32_16x16x32_bf16(af, wof[8 + ks], a1, 0, 0, 0);
        }

        int trow[4];
#pragma unroll
        for (int r = 0; r < 4; r++) trow[r] = (int)order[base + rt * 16 + quad * 4 + r];

#pragma unroll
        for (int r = 0; r < 4; r++) {
            a0[r] += x[(size_t)trow[r] * 32 + col] + bo0;
            a1[r] += x[(size_t)trow[r] * 32 + 16 + col] + bo1;
        }

        f32x4 xn0, xn1;
#pragma unroll
        for (int r = 0; r < 4; r++) {
            float s = a0[r] + a1[r];
            s += __shfl_xor(s, 1); s += __shfl_xor(s, 2); s += __shfl_xor(s, 4); s += __shfl_xor(s, 8);
            float mu = s * (1.0f / 32.0f);
            float c0 = a0[r] - mu, c1 = a1[r] - mu;
            float v = c0 * c0 + c1 * c1;
            v += __shfl_xor(v, 1); v += __shfl_xor(v, 2); v += __shfl_xor(v, 4); v += __shfl_xor(v, 8);
            float rstd = rsqrtf(v * (1.0f / 32.0f) + 1e-5f);
            xn0[r] = c0 * rstd * g20 + be20;
            xn1[r] = c1 * rstd * g21 + be21;
        }

#pragma unroll
        for (int r = 0; r < 4; r++) {
            strip[wave][quad * 4 + r][col]      = f2bf(xn0[r]);
            strip[wave][quad * 4 + r][col + 16] = f2bf(xn1[r]);
        }
        bf16x8 af1 = *(const bf16x8*)&strip[wave][col][quad * 8];
        f32x4 z = { 0.f, 0.f, 0.f, 0.f };
        f32x4 h0 = __builtin_amdgcn_mfma_f32_16x16x32_bf16(af1, w1f[0], z, 0, 0, 0);
        f32x4 h1 = __builtin_amdgcn_mfma_f32_16x16x32_bf16(af1, w1f[1], z, 0, 0, 0);
#pragma unroll
        for (int r = 0; r < 4; r++) {
            h0[r] = fmaxf(h0[r] + fb10, 0.f);
            h1[r] = fmaxf(h1[r] + fb11, 0.f);
        }

#pragma unroll
        for (int r = 0; r < 4; r++) {
            strip[wave][quad * 4 + r][col]      = f2bf(h0[r]);
            strip[wave][quad * 4 + r][col + 16] = f2bf(h1[r]);
        }
        bf16x8 af2 = *(const bf16x8*)&strip[wave][col][quad * 8];
        f32x4 f0 = __builtin_amdgcn_mfma_f32_16x16x32_bf16(af2, w2f[0], z, 0, 0, 0);
        f32x4 f1 = __builtin_amdgcn_mfma_f32_16x16x32_bf16(af2, w2f[1], z, 0, 0, 0);

#pragma unroll
        for (int r = 0; r < 4; r++) {
            out[(size_t)trow[r] * 32 + col]      = a0[r] + f0[r] + fb20;
            out[(size_t)trow[r] * 32 + 16 + col] = a1[r] + f1[r] + fb21;
        }
    }
}

extern "C" void kernel_launch(void* const* d_in, const int* in_sizes, int n_in,
                              void* d_out, int out_size, void* d_ws, size_t ws_size,
                              hipStream_t stream) {
    (void)in_sizes; (void)n_in; (void)out_size; (void)ws_size;
    const float* x      = (const float*)d_in[0];
    const float* coords = (const float*)d_in[1];
    const float* wq     = (const float*)d_in[2];
    const float* wk     = (const float*)d_in[3];
    const float* wv     = (const float*)d_in[4];
    const float* w_rpe  = (const float*)d_in[5];
    const float* w_out  = (const float*)d_in[6];
    const float* b_out  = (const float*)d_in[7];
    const float* g1     = (const float*)d_in[8];
    const float* be1    = (const float*)d_in[9];
    const float* g2     = (const float*)d_in[10];
    const float* be2    = (const float*)d_in[11];
    const float* ffw1   = (const float*)d_in[12];
    const float* ffb1   = (const float*)d_in[13];
    const float* ffw2   = (const float*)d_in[14];
    const float* ffb2   = (const float*)d_in[15];
    float* out = (float*)d_out;

    char* ws = (char*)d_ws;
    unsigned int* hist  = (unsigned int*)(ws);                       // 64K u32
    unsigned int* excl  = (unsigned int*)(ws + 256 * 1024);          // 64K u32
    unsigned int* aux   = (unsigned int*)(ws + 512 * 1024);          // 256 u32
    unsigned int* memb  = (unsigned int*)(ws + 768 * 1024);          // 64K u32
    unsigned int* order = (unsigned int*)(ws + 1024 * 1024);         // 64K u32
    float*        w2    = (float*)(ws + 1280 * 1024);                // 16 f32
    unsigned short* wqkvb = (unsigned short*)(ws + 1536 * 1024);     // 48 KB
    unsigned short* woutb = wqkvb + 24576;
    unsigned short* ff1b  = woutb + 8192;
    unsigned short* ff2b  = ff1b + 1024;
    unsigned short* aobf = (unsigned short*)(ws + (size_t)100 * 1048576); // 32 MiB [(b*8+h)][256][32]

    hipMemsetAsync(hist, 0, 65536 * sizeof(unsigned int), stream);
    khist   <<<256, 256, 0, stream>>>(coords, hist);
    kscan1  <<<256, 256, 0, stream>>>(hist, excl, aux);
    kscan2  <<<1,   256, 0, stream>>>(aux);
    kscan3  <<<256, 256, 0, stream>>>(excl, aux);
    kscatter<<<256, 256, 0, stream>>>(coords, excl, memb);
    krank   <<<256, 256, 0, stream>>>(coords, excl, memb, order);
    kwprep  <<<152, 256, 0, stream>>>(wq, wk, wv, w_out, ffw1, ffw2, w_rpe,
                                      wqkvb, woutb, ff1b, ff2b, w2);
    kattn   <<<2048,256, 0, stream>>>(x, g1, be1, wqkvb, order, coords, w2, aobf);
    kfinal  <<<512, 256, 0, stream>>>(x, aobf, order, woutb, b_out, g2, be2,
                                      ff1b, ffb1, ff2b, ffb2, out);
}